// Round 12
// baseline (241.521 us; speedup 1.0000x reference)
//
#include <hip/hip_runtime.h>
#include <hip/hip_bf16.h>

#define BATCH   32768
#define DIM     2048
#define NHEADS  28
#define NCOLS   280
#define LOSS_SCALE (1.0f / (float)(BATCH * NHEADS))

typedef __attribute__((ext_vector_type(8))) short short8;
typedef __attribute__((ext_vector_type(4))) short short4v;
typedef __attribute__((ext_vector_type(4))) float f32x4;

__device__ __forceinline__ short f2bf(float f) {
    union { __hip_bfloat16 h; short s; } u; u.h = __float2bfloat16(f); return u.s;
}

// ---------------------------------------------------------------------------
// W pre-swizzle (R8-proven): W [280][2048] f32 -> Wswz bf16, 16x16x32 B-frag
// order: short idx = (nt*64 + kt32)*512 + lane*8 + j
//   n = nt*16 + (lane&15), d = kt32*32 + (lane>>4)*8 + j
// ---------------------------------------------------------------------------
__global__ void mvh_swz(const float* __restrict__ W, short* __restrict__ Wswz) {
    int t = blockIdx.x * 256 + threadIdx.x;      // 73728 threads
    int lane = t & 63;
    int ks = (t >> 6) & 63;
    int nt = t >> 12;                            // 0..17
    int n = nt * 16 + (lane & 15);
    int d = ks * 32 + (lane >> 4) * 8;
    short8 v;
    #pragma unroll
    for (int j = 0; j < 8; j++) v[j] = 0;
    if (n < NCOLS) {
        const float* src = W + (size_t)n * DIM + d;
        #pragma unroll
        for (int j = 0; j < 8; j++) v[j] = f2bf(src[j]);
    }
    *(short8*)(Wswz + (size_t)t * 8) = v;
}

// ---------------------------------------------------------------------------
// GEMM: logits[b][n] = sum_d hidden[b][d]*W[n][d] + bias[n]
// grid 512 x 512 threads (8 waves = 4 wsub x 2 nh), 2 blocks/CU (16 waves).
// BM=64, BK=256 floats, 8 phases. KEY CHANGE (the one untested variable):
// A is streamed WAVE-LINEARLY — each wave-instruction reads one row's 1KB
// contiguous phase-segment (lane=16B, 64 lanes = the full segment). Every
// prior round issued 16-128B scattered segments per wave-instr and hit
// ~2.1 TB/s; abench1 proved 1KB-contiguous wave reads sustain ~7 TB/s.
// A: regs -> bf16 row-major LDS [64][512B] with XOR swizzle
//    (kb ^ ((row&15)<<4)): writes bank-free, frag reads conflict-free.
// B: R2/R8-proven direct reg-loads from L2-resident frag-ordered Wswz,
//    transient per-MFMA (no LDS, no persistent b[] WAR hazard).
// acc = 9 x f32x4 = 36 VGPR; ~100 total -> 2 blocks/CU at (512,4).
// ---------------------------------------------------------------------------
#define SB0() __builtin_amdgcn_sched_barrier(0)

__global__ __launch_bounds__(512, 4)
void mvh_gemm(const float* __restrict__ hidden, const short* __restrict__ Wswz,
              const float* __restrict__ bias, float* __restrict__ logits) {
    __shared__ __align__(16) char lds[65536];    // 2 x 32KB A-phase buffers

    const int tid  = threadIdx.x;
    const int lane = tid & 63;
    const int wave = tid >> 6;          // 0..7
    const int nh   = wave & 1;          // 144-col half (9 frags)
    const int wsub = wave >> 1;         // 0..3: 16-row slice
    const int rowbase = blockIdx.x * 64;

    // Streaming map: chunk c, phase p: wave rb covers row c*8+rb; lane kq
    // holds 16B at float-offset kq*4 of the row's 1KB segment.
    const int rb = tid >> 6;
    const int kq = tid & 63;
    const float* gA = hidden + (size_t)(rowbase + rb) * DIM + kq * 4;

    // A-frag read constants: row = wsub*16 + (lane&15), oct = lane>>4.
    const int arow = wsub * 16 + (lane & 15);
    const int aswz = (lane & 15) << 4;
    const int aoct16 = (lane >> 4) << 4;

    // B base: frag nt = nh*9+nf, k-tile kt32 = p*8+s.
    const short* bbase = Wswz + (size_t)(nh * 9) * 64 * 512 + (size_t)lane * 8;

    f32x4 acc[9];
    #pragma unroll
    for (int n = 0; n < 9; n++) acc[n] = (f32x4)0.0f;

    f32x4 a0, a1, a2, a3;   // 4-chunk in-flight batch (named, rule #20)

#define LCH(r, c, ph) do { r = *(const f32x4*)(gA + (size_t)(c) * 8 * DIM + (ph) * 256); } while (0)

#define WCH(dst, c, r) do { \
    int row_ = (c) * 8 + rb; \
    int ad_ = row_ * 512 + ((kq * 8) ^ ((row_ & 15) << 4)); \
    short4v w_; \
    w_[0] = f2bf(r[0]); w_[1] = f2bf(r[1]); w_[2] = f2bf(r[2]); w_[3] = f2bf(r[3]); \
    *(short4v*)((dst) + ad_) = w_; \
} while (0)

#define CST(Ab, p, s) do { \
    short8 af_ = *(const short8*)((Ab) + arow * 512 + (((s) * 64 + aoct16) ^ aswz)); \
    _Pragma("unroll") \
    for (int nf_ = 0; nf_ < 9; nf_++) { \
        short8 bf_ = *(const short8*)(bbase + ((size_t)nf_ * 64 + (p) * 8 + (s)) * 512); \
        acc[nf_] = __builtin_amdgcn_mfma_f32_16x16x32_bf16(af_, bf_, acc[nf_], 0, 0, 0); \
    } \
} while (0)

    // ---- prologue: slab 0 -> buf0 ----
    LCH(a0, 0, 0); LCH(a1, 1, 0); LCH(a2, 2, 0); LCH(a3, 3, 0);
    WCH(lds, 0, a0); WCH(lds, 1, a1); WCH(lds, 2, a2); WCH(lds, 3, a3);
    LCH(a0, 4, 0); LCH(a1, 5, 0); LCH(a2, 6, 0); LCH(a3, 7, 0);
    WCH(lds, 4, a0); WCH(lds, 5, a1); WCH(lds, 6, a2); WCH(lds, 7, a3);
    __syncthreads();

    // ---- 8 phases: compute slab p, stream slab p+1 ----
    #pragma unroll 1
    for (int p = 0; p < 8; p++) {
        char* Ac = lds + (p & 1) * 32768;
        char* An = lds + ((p & 1) ^ 1) * 32768;
        if (p < 7) { LCH(a0, 0, p + 1); LCH(a1, 1, p + 1); LCH(a2, 2, p + 1); LCH(a3, 3, p + 1); }
        SB0();
        CST(Ac, p, 0); CST(Ac, p, 1); CST(Ac, p, 2); CST(Ac, p, 3);
        SB0();
        if (p < 7) {
            WCH(An, 0, a0); WCH(An, 1, a1); WCH(An, 2, a2); WCH(An, 3, a3);
            LCH(a0, 4, p + 1); LCH(a1, 5, p + 1); LCH(a2, 6, p + 1); LCH(a3, 7, p + 1);
        }
        SB0();
        CST(Ac, p, 4); CST(Ac, p, 5); CST(Ac, p, 6); CST(Ac, p, 7);
        SB0();
        if (p < 7) { WCH(An, 4, a0); WCH(An, 5, a1); WCH(An, 6, a2); WCH(An, 7, a3); }
        __syncthreads();
    }

#undef LCH
#undef WCH
#undef CST

    // ---- epilogue: bias + store (R8-proven 16x16 C layout) ----
    #pragma unroll
    for (int nf = 0; nf < 9; nf++) {
        int c = (nh * 9 + nf) * 16 + (lane & 15);
        if (c < NCOLS) {
            float bv = bias[c];
            int row0 = rowbase + wsub * 16 + (lane >> 4) * 4;
            #pragma unroll
            for (int r = 0; r < 4; r++)
                logits[(size_t)(row0 + r) * NCOLS + c] = acc[nf][r] + bv;
        }
    }
}

// ---------------------------------------------------------------------------
// Loss: one thread per (row, head). nll = logsumexp(10) - x[label].
// ---------------------------------------------------------------------------
__global__ __launch_bounds__(256)
void mvh_loss(const float* __restrict__ logits, const int* __restrict__ labels,
              float* __restrict__ loss_out) {
    int gid = blockIdx.x * 256 + threadIdx.x;    // 917504 = 3584*256 exactly
    const float* p = logits + (size_t)gid * 10;
    float x[10];
    #pragma unroll
    for (int j = 0; j < 10; j++) x[j] = p[j];
    float m = x[0];
    #pragma unroll
    for (int j = 1; j < 10; j++) m = fmaxf(m, x[j]);
    float s = 0.0f;
    #pragma unroll
    for (int j = 0; j < 10; j++) s += __expf(x[j] - m);
    int lab = labels[gid];
    float xl = x[0];
    #pragma unroll
    for (int j = 1; j < 10; j++) xl = (lab == j) ? x[j] : xl;
    float nll = m + __logf(s) - xl;

    #pragma unroll
    for (int off = 32; off > 0; off >>= 1)
        nll += __shfl_down(nll, off, 64);

    __shared__ float part[4];
    int lane = threadIdx.x & 63, wv = threadIdx.x >> 6;
    if (lane == 0) part[wv] = nll;
    __syncthreads();
    if (threadIdx.x == 0)
        atomicAdd(loss_out, (part[0] + part[1] + part[2] + part[3]) * LOSS_SCALE);
}

extern "C" void kernel_launch(void* const* d_in, const int* in_sizes, int n_in,
                              void* d_out, int out_size, void* d_ws, size_t ws_size,
                              hipStream_t stream) {
    const float* hidden = (const float*)d_in[0];
    const int* labels   = (const int*)d_in[1];
    const float* W      = (const float*)d_in[2];
    const float* bias   = (const float*)d_in[3];
    float* out = (float*)d_out;
    short* Wswz = (short*)d_ws;   // 589824 bf16 = 1.18 MB

    (void)hipMemsetAsync(d_out, 0, sizeof(float), stream);     // zero loss accumulator
    mvh_swz<<<288, 256, 0, stream>>>(W, Wswz);
    mvh_gemm<<<512, 512, 0, stream>>>(hidden, Wswz, bias, out + 1);
    mvh_loss<<<3584, 256, 0, stream>>>(out + 1, labels, out);
}

// Round 13
// 241.143 us; speedup vs baseline: 1.0016x; 1.0016x over previous
//
#include <hip/hip_runtime.h>
#include <hip/hip_bf16.h>

#define BATCH   32768
#define DIM     2048
#define NHEADS  28
#define NCOLS   280
#define LOSS_SCALE (1.0f / (float)(BATCH * NHEADS))

typedef __attribute__((ext_vector_type(8))) short short8;
typedef __attribute__((ext_vector_type(4))) float f32x4;

__device__ __forceinline__ short f2bf(float f) {
    union { __hip_bfloat16 h; short s; } u; u.h = __float2bfloat16(f); return u.s;
}

// ---------------------------------------------------------------------------
// W pre-swizzle (R8-proven): W [280][2048] f32 -> Wswz bf16, 16x16x32 B-frag
// order: short idx = (nt*64 + kt)*512 + lane*8 + j
//   n = nt*16 + (lane&15), d = kt*32 + (lane>>4)*8 + j
// ---------------------------------------------------------------------------
__global__ void mvh_swz(const float* __restrict__ W, short* __restrict__ Wswz) {
    int t = blockIdx.x * 256 + threadIdx.x;      // 73728 threads
    int lane = t & 63;
    int ks = (t >> 6) & 63;
    int nt = t >> 12;                            // 0..17
    int n = nt * 16 + (lane & 15);
    int d = ks * 32 + (lane >> 4) * 8;
    short8 v;
    #pragma unroll
    for (int j = 0; j < 8; j++) v[j] = 0;
    if (n < NCOLS) {
        const float* src = W + (size_t)n * DIM + d;
        #pragma unroll
        for (int j = 0; j < 8; j++) v[j] = f2bf(src[j]);
    }
    *(short8*)(Wswz + (size_t)t * 8) = v;
}

// ---------------------------------------------------------------------------
// GEMM, K-split x2: block bid = (rowblk<<1)|kh computes rows rowblk*64,
// k in [kh*1024, kh*1024+1024), and atomicAdds its partial into logits
// (pre-zeroed by memset; kh==0 blocks add bias).
// grid 1024 x 512 thr (8 waves = 4 wsub x 2 nh) -> 3 blocks/CU = 24 waves/CU
// (the duty-cycle fix: 3 independent barrier-groups per CU keep the VMEM
// queue fed while any one block drains at its __syncthreads).
// BM=64, BK=32, 32 tiles/block. A: fp32 via global_load_lds, granule-XOR
// swizzle (source-side chunk^=(row&7)) -> conflict-free frag reads.
// B: global_load_lds from L2-resident frag-ordered Wswz. Both dbuf'd;
// ONE __syncthreads per tile. acc = 9 x f32x4 = 36 VGPR.
// ---------------------------------------------------------------------------
#define A_T 8192
#define B_T 18432

#define GLOAD(src, dst) __builtin_amdgcn_global_load_lds( \
    (const __attribute__((address_space(1))) void*)(src), \
    (__attribute__((address_space(3))) void*)(dst), 16, 0, 0)

__global__ __launch_bounds__(512, 6)
void mvh_gemm(const float* __restrict__ hidden, const short* __restrict__ Wswz,
              const float* __restrict__ bias, float* __restrict__ logits) {
    __shared__ __align__(16) char lds[2 * A_T + 2 * B_T];   // 53248 B
    char* A0 = lds;
    char* A1 = lds + A_T;
    char* B0 = lds + 2 * A_T;
    char* B1 = lds + 2 * A_T + B_T;

    const int tid  = threadIdx.x;
    const int lane = tid & 63;
    const int wave = tid >> 6;          // 0..7
    const int nh   = wave & 1;          // 144-col half (9 frags)
    const int wsub = wave >> 1;         // 0..3: 16-row slice
    const int kh   = blockIdx.x & 1;    // K half
    const int rowbase = (blockIdx.x >> 1) * 64;
    const int ktb  = kh * 32;           // first k-tile of this half

    // A staging: thread -> row ar=tid>>3, granule agi=tid&7 (16B chunks of 4
    // floats). Source chunk = agi ^ (ar&7)  (inverse swizzle), dst = tid*16.
    const int ar  = tid >> 3;
    const int agi = tid & 7;
    const float* gA = hidden + (size_t)(rowbase + ar) * DIM + ktb * 32
                    + (agi ^ (ar & 7)) * 4;

    // A frag read: row = wsub*16+(lane&15), octet = lane>>4; chunks 2o,2o+1
    // live at LDS slots row*8 + (chunk ^ (row&7)).
    const int arow = wsub * 16 + (lane & 15);
    const int aoct = lane >> 4;
    const int asw  = arow & 7;
    const int alo  = (arow * 8 + ((2 * aoct)     ^ asw)) * 16;
    const int ahi  = (arow * 8 + ((2 * aoct + 1) ^ asw)) * 16;

    f32x4 acc[9];
    #pragma unroll
    for (int n = 0; n < 9; n++) acc[n] = (f32x4)0.0f;

#define STAGE_A(dst, t) GLOAD(gA + (t) * 32, (dst) + tid * 16)

#define STAGE_B(dst, t) do { \
    _Pragma("unroll") \
    for (int i_ = 0; i_ < 3; i_++) { \
        if (i_ < 2 || tid < 128) { \
            int g_ = (i_ < 2) ? (i_ * 512 + tid) : (1024 + tid); \
            const short* gp_ = Wswz + (size_t)((g_ >> 6) * 64 + ktb + (t)) * 512 + (g_ & 63) * 8; \
            GLOAD(gp_, (dst) + g_ * 16); \
        } \
    } \
} while (0)

#define COMPUTE(Ab, Bb) do { \
    f32x4 lo_ = *(const f32x4*)((Ab) + alo); \
    f32x4 hi_ = *(const f32x4*)((Ab) + ahi); \
    short8 af_; \
    _Pragma("unroll") \
    for (int j_ = 0; j_ < 4; j_++) { af_[j_] = f2bf(lo_[j_]); af_[4 + j_] = f2bf(hi_[j_]); } \
    _Pragma("unroll") \
    for (int nf_ = 0; nf_ < 9; nf_++) { \
        short8 bf_ = *(const short8*)((Bb) + (nh * 9 + nf_) * 1024 + lane * 16); \
        acc[nf_] = __builtin_amdgcn_mfma_f32_16x16x32_bf16(af_, bf_, acc[nf_], 0, 0, 0); \
    } \
} while (0)

    // ---- prologue: tile 0 -> bufs 0 ----
    STAGE_A(A0, 0); STAGE_B(B0, 0);

    // ---- main: 32 tiles, ONE __syncthreads per tile ----
    #pragma unroll 1
    for (int tp = 0; tp < 16; tp++) {
        const int t = tp * 2;
        __syncthreads();                              // tile t staged
        if (t + 1 < 32) { STAGE_A(A1, t + 1); STAGE_B(B1, t + 1); }
        COMPUTE(A0, B0);
        __syncthreads();                              // tile t+1 staged
        if (t + 2 < 32) { STAGE_A(A0, t + 2); STAGE_B(B0, t + 2); }
        COMPUTE(A1, B1);
    }

#undef STAGE_A
#undef STAGE_B
#undef COMPUTE

    // ---- epilogue: atomic accumulate partial (+bias for kh==0) ----
    #pragma unroll
    for (int nf = 0; nf < 9; nf++) {
        int c = (nh * 9 + nf) * 16 + (lane & 15);
        if (c < NCOLS) {
            float bv = (kh == 0) ? bias[c] : 0.0f;
            int row0 = rowbase + wsub * 16 + aoct * 4;
            #pragma unroll
            for (int r = 0; r < 4; r++)
                atomicAdd(&logits[(size_t)(row0 + r) * NCOLS + c], acc[nf][r] + bv);
        }
    }
}

// ---------------------------------------------------------------------------
// Loss: one thread per (row, head). nll = logsumexp(10) - x[label].
// ---------------------------------------------------------------------------
__global__ __launch_bounds__(256)
void mvh_loss(const float* __restrict__ logits, const int* __restrict__ labels,
              float* __restrict__ loss_out) {
    int gid = blockIdx.x * 256 + threadIdx.x;    // 917504 = 3584*256 exactly
    const float* p = logits + (size_t)gid * 10;
    float x[10];
    #pragma unroll
    for (int j = 0; j < 10; j++) x[j] = p[j];
    float m = x[0];
    #pragma unroll
    for (int j = 1; j < 10; j++) m = fmaxf(m, x[j]);
    float s = 0.0f;
    #pragma unroll
    for (int j = 0; j < 10; j++) s += __expf(x[j] - m);
    int lab = labels[gid];
    float xl = x[0];
    #pragma unroll
    for (int j = 1; j < 10; j++) xl = (lab == j) ? x[j] : xl;
    float nll = m + __logf(s) - xl;

    #pragma unroll
    for (int off = 32; off > 0; off >>= 1)
        nll += __shfl_down(nll, off, 64);

    __shared__ float part[4];
    int lane = threadIdx.x & 63, wv = threadIdx.x >> 6;
    if (lane == 0) part[wv] = nll;
    __syncthreads();
    if (threadIdx.x == 0)
        atomicAdd(loss_out, (part[0] + part[1] + part[2] + part[3]) * LOSS_SCALE);
}

extern "C" void kernel_launch(void* const* d_in, const int* in_sizes, int n_in,
                              void* d_out, int out_size, void* d_ws, size_t ws_size,
                              hipStream_t stream) {
    const float* hidden = (const float*)d_in[0];
    const int* labels   = (const int*)d_in[1];
    const float* W      = (const float*)d_in[2];
    const float* bias   = (const float*)d_in[3];
    float* out = (float*)d_out;
    short* Wswz = (short*)d_ws;   // 589824 bf16 = 1.18 MB

    // zero loss accumulator AND logits (atomic-accumulate base)
    (void)hipMemsetAsync(d_out, 0, (size_t)out_size * sizeof(float), stream);
    mvh_swz<<<288, 256, 0, stream>>>(W, Wswz);
    mvh_gemm<<<1024, 512, 0, stream>>>(hidden, Wswz, bias, out + 1);
    mvh_loss<<<3584, 256, 0, stream>>>(out + 1, labels, out);
}

// Round 14
// 141.659 us; speedup vs baseline: 1.7049x; 1.7023x over previous
//
#include <hip/hip_runtime.h>
#include <hip/hip_bf16.h>

#define BATCH   32768
#define DIM     2048
#define NHEADS  28
#define NCOLS   280
#define LOSS_SCALE (1.0f / (float)(BATCH * NHEADS))

typedef __attribute__((ext_vector_type(8))) short short8;
typedef __attribute__((ext_vector_type(4))) float f32x4;

__device__ __forceinline__ short f2bf(float f) {
    union { __hip_bfloat16 h; short s; } u; u.h = __float2bfloat16(f); return u.s;
}

// ---------------------------------------------------------------------------
// W pre-swizzle (R8-proven): W [280][2048] f32 -> Wswz bf16, 16x16x32 B-frag
// order: short idx = (nt*64 + kt)*512 + lane*8 + j
//   n = nt*16 + (lane&15), d = kt*32 + (lane>>4)*8 + j
// ---------------------------------------------------------------------------
__global__ void mvh_swz(const float* __restrict__ W, short* __restrict__ Wswz) {
    int t = blockIdx.x * 256 + threadIdx.x;      // 73728 threads
    int lane = t & 63;
    int ks = (t >> 6) & 63;
    int nt = t >> 12;                            // 0..17
    int n = nt * 16 + (lane & 15);
    int d = ks * 32 + (lane >> 4) * 8;
    short8 v;
    #pragma unroll
    for (int j = 0; j < 8; j++) v[j] = 0;
    if (n < NCOLS) {
        const float* src = W + (size_t)n * DIM + d;
        #pragma unroll
        for (int j = 0; j < 8; j++) v[j] = f2bf(src[j]);
    }
    *(short8*)(Wswz + (size_t)t * 8) = v;
}

// ---------------------------------------------------------------------------
// GEMM: logits[b][n] = sum_d hidden[b][d]*W[n][d] + bias[n]
// grid 256 x 512 threads (8 waves = 4 wsub x 2 nh), 1 block/CU.
// BM=128, interval BK=64 floats (2 k-tiles of 32) -> 32 intervals TOTAL.
// THEORY (from 13 rounds): each barrier interval costs
// max(latency ~2000cy, payload/BW); all priors had <=26KB payloads
// (latency-bound, intervals add across blocks). Here payload/interval =
// 68.9KB (A 32KB HBM + B 36.9KB L2), transfer ~3200cy > latency, so the
// __syncthreads drain is nearly free and the loop runs at the HBM floor.
// A: fp32 global_load_lds DMA, granule-XOR swizzle (R13-proven, source-side).
// B: global_load_lds DMA from L2-resident frag-ordered Wswz (R8 order).
// Both double-buffered (136KB LDS); ONE __syncthreads per interval.
// acc = 2m x 9n f32x4 = 72 VGPR. No atomics; direct store + bias.
// ---------------------------------------------------------------------------
#define ABUF(b) ((b) * 32768)
#define BBUF(b) (65536 + (b) * 36864)

#define SB0() __builtin_amdgcn_sched_barrier(0)
#define GLOAD(src, dst) __builtin_amdgcn_global_load_lds( \
    (const __attribute__((address_space(1))) void*)(src), \
    (__attribute__((address_space(3))) void*)(dst), 16, 0, 0)

__global__ __launch_bounds__(512, 2)
void mvh_gemm(const float* __restrict__ hidden, const short* __restrict__ Wswz,
              const float* __restrict__ bias, float* __restrict__ logits) {
    __shared__ __align__(16) char lds[139264];   // 2x32KB A + 2x36.9KB B

    const int tid  = threadIdx.x;
    const int lane = tid & 63;
    const int wave = tid >> 6;          // 0..7
    const int nh   = wave & 1;          // col half (9 frags of 16)
    const int wsub = wave >> 1;         // 0..3: 32-row slice
    const int l15  = lane & 15;
    const int oct  = lane >> 4;         // 0..3
    const int rowbase = blockIdx.x * 128;

    // A frag-read constants (per m): row = wsub*32 + m*16 + l15,
    // granules (2*oct, 2*oct+1) ^ (row&7), 16B each, row pitch 128B/tile.
    const int arow0 = wsub * 32 + l15;
    const int arow1 = arow0 + 16;
    const int aoff0_lo = arow0 * 128 + (((2 * oct)     ^ (arow0 & 7)) << 4);
    const int aoff0_hi = arow0 * 128 + (((2 * oct + 1) ^ (arow0 & 7)) << 4);
    const int aoff1_lo = arow1 * 128 + (((2 * oct)     ^ (arow1 & 7)) << 4);
    const int aoff1_hi = arow1 * 128 + (((2 * oct + 1) ^ (arow1 & 7)) << 4);

    f32x4 acc[2][9];
    #pragma unroll
    for (int m = 0; m < 2; m++)
        #pragma unroll
        for (int n = 0; n < 9; n++) acc[m][n] = (f32x4)0.0f;

    // ---- staging: interval iv covers k-tiles 2iv, 2iv+1 ----
    // A: 2048 granules (g = tile*1024 + row*8 + gi), 4 issues/thread.
    // B: 2304 granules (g = kt*1152 + nf*64 + l), 4.5 issues/thread.
#define STAGE(b, iv) do { \
    const int kb_ = (iv) * 2; \
    _Pragma("unroll") \
    for (int j_ = 0; j_ < 4; j_++) { \
        int g_ = j_ * 512 + tid; \
        int tile_ = g_ >> 10, row_ = (g_ >> 3) & 127, gi_ = g_ & 7; \
        const float* sp_ = hidden + (size_t)(rowbase + row_) * DIM \
                          + (kb_ + tile_) * 32 + ((gi_ ^ (row_ & 7)) << 2); \
        GLOAD(sp_, lds + ABUF(b) + g_ * 16); \
    } \
    _Pragma("unroll") \
    for (int j_ = 0; j_ < 5; j_++) { \
        if (j_ < 4 || tid < 256) { \
            int g_ = (j_ < 4) ? (j_ * 512 + tid) : (2048 + tid); \
            int kt_ = (g_ >= 1152) ? 1 : 0; \
            int gg_ = g_ - kt_ * 1152; \
            const short* sp_ = Wswz + (size_t)((gg_ >> 6) * 64 + kb_ + kt_) * 512 \
                              + (gg_ & 63) * 8; \
            GLOAD(sp_, lds + BBUF(b) + g_ * 16); \
        } \
    } \
} while (0)

#define COMPUTE(b) do { \
    _Pragma("unroll") \
    for (int kt_ = 0; kt_ < 2; kt_++) { \
        const char* At_ = lds + ABUF(b) + kt_ * 16384; \
        short8 af0_, af1_; \
        { \
            f32x4 lo_ = *(const f32x4*)(At_ + aoff0_lo); \
            f32x4 hi_ = *(const f32x4*)(At_ + aoff0_hi); \
            _Pragma("unroll") \
            for (int j_ = 0; j_ < 4; j_++) { af0_[j_] = f2bf(lo_[j_]); af0_[4 + j_] = f2bf(hi_[j_]); } \
        } \
        { \
            f32x4 lo_ = *(const f32x4*)(At_ + aoff1_lo); \
            f32x4 hi_ = *(const f32x4*)(At_ + aoff1_hi); \
            _Pragma("unroll") \
            for (int j_ = 0; j_ < 4; j_++) { af1_[j_] = f2bf(lo_[j_]); af1_[4 + j_] = f2bf(hi_[j_]); } \
        } \
        _Pragma("unroll") \
        for (int nf_ = 0; nf_ < 9; nf_++) { \
            short8 bf_ = *(const short8*)(lds + BBUF(b) + kt_ * 18432 \
                          + (nh * 9 + nf_) * 1024 + lane * 16); \
            acc[0][nf_] = __builtin_amdgcn_mfma_f32_16x16x32_bf16(af0_, bf_, acc[0][nf_], 0, 0, 0); \
            acc[1][nf_] = __builtin_amdgcn_mfma_f32_16x16x32_bf16(af1_, bf_, acc[1][nf_], 0, 0, 0); \
        } \
    } \
} while (0)

    // ---- prologue ----
    STAGE(0, 0);
    __syncthreads();

    // ---- main: 32 fat intervals, one __syncthreads each ----
    #pragma unroll 1
    for (int i = 0; i < 32; i++) {
        if (i < 31) STAGE((i + 1) & 1, i + 1);
        SB0();
        COMPUTE(i & 1);
        __syncthreads();
    }

#undef STAGE
#undef COMPUTE

    // ---- epilogue: bias + direct store (R8-proven C layout) ----
    #pragma unroll
    for (int nf = 0; nf < 9; nf++) {
        int c = (nh * 9 + nf) * 16 + l15;
        if (c < NCOLS) {
            float bv = bias[c];
            #pragma unroll
            for (int m = 0; m < 2; m++) {
                int row0 = rowbase + wsub * 32 + m * 16 + oct * 4;
                #pragma unroll
                for (int r = 0; r < 4; r++)
                    logits[(size_t)(row0 + r) * NCOLS + c] = acc[m][nf][r] + bv;
            }
        }
    }
}

// ---------------------------------------------------------------------------
// Loss: one thread per (row, head). nll = logsumexp(10) - x[label].
// ---------------------------------------------------------------------------
__global__ __launch_bounds__(256)
void mvh_loss(const float* __restrict__ logits, const int* __restrict__ labels,
              float* __restrict__ loss_out) {
    int gid = blockIdx.x * 256 + threadIdx.x;    // 917504 = 3584*256 exactly
    const float* p = logits + (size_t)gid * 10;
    float x[10];
    #pragma unroll
    for (int j = 0; j < 10; j++) x[j] = p[j];
    float m = x[0];
    #pragma unroll
    for (int j = 1; j < 10; j++) m = fmaxf(m, x[j]);
    float s = 0.0f;
    #pragma unroll
    for (int j = 0; j < 10; j++) s += __expf(x[j] - m);
    int lab = labels[gid];
    float xl = x[0];
    #pragma unroll
    for (int j = 1; j < 10; j++) xl = (lab == j) ? x[j] : xl;
    float nll = m + __logf(s) - xl;

    #pragma unroll
    for (int off = 32; off > 0; off >>= 1)
        nll += __shfl_down(nll, off, 64);

    __shared__ float part[4];
    int lane = threadIdx.x & 63, wv = threadIdx.x >> 6;
    if (lane == 0) part[wv] = nll;
    __syncthreads();
    if (threadIdx.x == 0)
        atomicAdd(loss_out, (part[0] + part[1] + part[2] + part[3]) * LOSS_SCALE);
}

extern "C" void kernel_launch(void* const* d_in, const int* in_sizes, int n_in,
                              void* d_out, int out_size, void* d_ws, size_t ws_size,
                              hipStream_t stream) {
    const float* hidden = (const float*)d_in[0];
    const int* labels   = (const int*)d_in[1];
    const float* W      = (const float*)d_in[2];
    const float* bias   = (const float*)d_in[3];
    float* out = (float*)d_out;
    short* Wswz = (short*)d_ws;   // 589824 bf16 = 1.18 MB

    (void)hipMemsetAsync(d_out, 0, sizeof(float), stream);     // zero loss accumulator
    mvh_swz<<<288, 256, 0, stream>>>(W, Wswz);
    mvh_gemm<<<256, 512, 0, stream>>>(hidden, Wswz, bias, out + 1);
    mvh_loss<<<3584, 256, 0, stream>>>(out + 1, labels, out);
}